// Round 1
// baseline (714.292 us; speedup 1.0000x reference)
//
#include <hip/hip_runtime.h>
#include <cstdint>
#include <cstddef>

// Problem constants
#define BB 64
#define NN_ 4096
#define DIN 256
#define KK 20
#define DS 64

using f32x4  = __attribute__((ext_vector_type(4))) float;
using bf16x8 = __attribute__((ext_vector_type(8))) short;

__device__ __forceinline__ float bflo(unsigned int u){ return __uint_as_float(u << 16); }
__device__ __forceinline__ float bfhi(unsigned int u){ return __uint_as_float(u & 0xffff0000u); }
__device__ __forceinline__ unsigned short f2bf(float f){
  unsigned int u = __float_as_uint(f);
  unsigned int r = (u + 0x7fffu + ((u >> 16) & 1u)) >> 16;
  return (unsigned short)r;
}

// XOR swizzle: rows are 512B; toggle 16B-slot bits with row&7 -> 2-way banked (free)
#define SWZ(o) ((o) ^ ((((o) >> 9) & 7) << 4))

// ---------------------------------------------------------------------------
// Build Wt (128 x 256 bf16): row n<64 = Wk column n, row n>=64 = Wv column n-64
__global__ void k_wt(const float* __restrict__ Wk, const float* __restrict__ Wv,
                     unsigned short* __restrict__ Wt){
  int idx = blockIdx.x * 256 + threadIdx.x;   // 32768 total
  int n = idx >> 8, kk = idx & 255;
  float w = (n < 64) ? Wk[kk * 64 + n] : Wv[kk * 64 + (n - 64)];
  Wt[idx] = f2bf(w);
}

// slots = mu + exp(log_sigma) * noise
__global__ void k_init(const float* __restrict__ noise, const float* __restrict__ mu,
                       const float* __restrict__ lsig, float* __restrict__ slots){
  int idx = blockIdx.x * 256 + threadIdx.x;   // 81920 total
  int d = idx & 63;
  slots[idx] = mu[d] + __expf(lsig[d]) * noise[idx];
}

// ---------------------------------------------------------------------------
// Fused LN + (x@Wk | x@Wv) -> kv bf16 [B*N][128]. BM=64 rows/block, two 64-col passes.
__global__ __launch_bounds__(256) void k_lnkv(
    const float* __restrict__ x, const float* __restrict__ lng, const float* __restrict__ lnb,
    const unsigned short* __restrict__ Wt, unsigned short* __restrict__ kv){
  extern __shared__ char smem[];
  char* As = smem;            // 64 x 256 bf16, swizzled (32KB)
  char* Bs = smem + 32768;    // 64 x 256 bf16, swizzled (32KB)
  const int t = threadIdx.x;
  const int lane = t & 63, w = t >> 6;
  const int gm0 = blockIdx.x * 64;

  const float4 g4 = *(const float4*)(lng + lane * 4);
  const float4 b4 = *(const float4*)(lnb + lane * 4);

  // --- stage A: LayerNorm rows -> bf16 LDS (wave w handles rows w*16..w*16+15)
  #pragma unroll
  for (int bb = 0; bb < 2; ++bb){
    float4 xv[8];
    #pragma unroll
    for (int j = 0; j < 8; ++j){
      int r = w * 16 + bb * 8 + j;
      xv[j] = *(const float4*)(x + (size_t)(gm0 + r) * 256 + lane * 4);
    }
    #pragma unroll
    for (int j = 0; j < 8; ++j){
      int r = w * 16 + bb * 8 + j;
      float4 v = xv[j];
      float s  = v.x + v.y + v.z + v.w;
      float s2 = v.x * v.x + v.y * v.y + v.z * v.z + v.w * v.w;
      #pragma unroll
      for (int off = 32; off >= 1; off >>= 1){
        s  += __shfl_xor(s,  off);
        s2 += __shfl_xor(s2, off);
      }
      float mean = s * (1.f / 256.f);
      float var  = s2 * (1.f / 256.f) - mean * mean;
      float rstd = rsqrtf(var + 1e-5f);
      ushort4 pk;
      pk.x = f2bf((v.x - mean) * rstd * g4.x + b4.x);
      pk.y = f2bf((v.y - mean) * rstd * g4.y + b4.y);
      pk.z = f2bf((v.z - mean) * rstd * g4.z + b4.z);
      pk.w = f2bf((v.w - mean) * rstd * g4.w + b4.w);
      int off8 = r * 512 + lane * 8;
      *(ushort4*)(As + SWZ(off8)) = pk;
    }
  }
  // --- stage B pass 0 (Wt rows 0..63)
  {
    const char* wp = (const char*)Wt;
    #pragma unroll
    for (int j = 0; j < 8; ++j){
      int c = t + 256 * j;
      *(uint4*)(Bs + SWZ(c * 16)) = *(const uint4*)(wp + c * 16);
    }
  }

  const int wm = w >> 1, wn = w & 1;
  const int l15 = lane & 15, l4 = lane >> 4;

  #pragma unroll 1
  for (int pass = 0; pass < 2; ++pass){
    if (pass == 1){
      __syncthreads();  // pass-0 MFMA done reading Bs
      const char* wp = (const char*)(Wt + 64 * 256);
      #pragma unroll
      for (int j = 0; j < 8; ++j){
        int c = t + 256 * j;
        *(uint4*)(Bs + SWZ(c * 16)) = *(const uint4*)(wp + c * 16);
      }
    }
    __syncthreads();

    f32x4 acc[2][2];
    #pragma unroll
    for (int i = 0; i < 2; ++i)
      #pragma unroll
      for (int j = 0; j < 2; ++j)
        acc[i][j] = (f32x4){0.f, 0.f, 0.f, 0.f};

    #pragma unroll
    for (int kk = 0; kk < 8; ++kk){
      bf16x8 a[2], bfr[2];
      #pragma unroll
      for (int i = 0; i < 2; ++i){
        int ar = wm * 32 + i * 16 + l15;
        a[i]   = *(const bf16x8*)(As + SWZ(ar * 512 + kk * 64 + l4 * 16));
        int br = wn * 32 + i * 16 + l15;
        bfr[i] = *(const bf16x8*)(Bs + SWZ(br * 512 + kk * 64 + l4 * 16));
      }
      #pragma unroll
      for (int i = 0; i < 2; ++i)
        #pragma unroll
        for (int j = 0; j < 2; ++j)
          acc[i][j] = __builtin_amdgcn_mfma_f32_16x16x32_bf16(a[i], bfr[j], acc[i][j], 0, 0, 0);
    }
    // store: D layout col=lane&15, row=(lane>>4)*4+reg
    #pragma unroll
    for (int i = 0; i < 2; ++i)
      #pragma unroll
      for (int j = 0; j < 2; ++j)
        #pragma unroll
        for (int reg = 0; reg < 4; ++reg){
          int grow = gm0 + wm * 32 + i * 16 + l4 * 4 + reg;
          int gcol = pass * 64 + wn * 32 + j * 16 + l15;
          kv[(size_t)grow * 128 + gcol] = f2bf(acc[i][j][reg]);
        }
  }
}

// ---------------------------------------------------------------------------
// q = LN(slots) @ Wq, one wave per (b,k)
__global__ __launch_bounds__(64) void k_slotq(
    const float* __restrict__ slots, const float* __restrict__ lng, const float* __restrict__ lnb,
    const float* __restrict__ Wq, float* __restrict__ qws){
  int bk = blockIdx.x, d = threadIdx.x;
  float s = slots[bk * 64 + d];
  float s1 = s, s2 = s * s;
  #pragma unroll
  for (int off = 32; off >= 1; off >>= 1){
    s1 += __shfl_xor(s1, off);
    s2 += __shfl_xor(s2, off);
  }
  float m = s1 * (1.f / 64.f);
  float var = s2 * (1.f / 64.f) - m * m;
  float rstd = rsqrtf(var + 1e-5f);
  float xn = (s - m) * rstd * lng[d] + lnb[d];
  __shared__ __align__(16) float xsh[64];
  xsh[d] = xn;
  __syncthreads();
  float q = 0.f;
  #pragma unroll
  for (int i = 0; i < 64; ++i) q += xsh[i] * Wq[i * 64 + d];
  qws[bk * 64 + d] = q;
}

// ---------------------------------------------------------------------------
// Per-(b, n-tile): dots -> softmax over K -> attn (write on last iter),
// S += sum_n attn, U += attn @ v  (normalization deferred)
__global__ __launch_bounds__(256) void k_attn(
    const unsigned short* __restrict__ kv, const float* __restrict__ qws,
    float* __restrict__ Sws, float* __restrict__ Uws,
    float* __restrict__ attn_out, int write_attn){
  __shared__ __align__(16) float qs[1280];          // [20][64]
  __shared__ __align__(16) float attnT[20][264];    // n-major rows, padded
  __shared__ __align__(16) float ured[4][64][21];
  const int t = threadIdx.x;
  const int b = blockIdx.y;
  const int n0 = blockIdx.x * 256;

  #pragma unroll
  for (int j = 0; j < 5; ++j) qs[t + 256 * j] = qws[b * 1280 + t + 256 * j];
  __syncthreads();

  // phase 1: one n per thread
  {
    int n = n0 + t;
    const uint4* kp = (const uint4*)(kv + ((size_t)(b * 4096 + n)) * 128);
    float kf[64];
    #pragma unroll
    for (int c = 0; c < 8; ++c){
      uint4 u = kp[c];
      kf[c*8+0]=bflo(u.x); kf[c*8+1]=bfhi(u.x);
      kf[c*8+2]=bflo(u.y); kf[c*8+3]=bfhi(u.y);
      kf[c*8+4]=bflo(u.z); kf[c*8+5]=bfhi(u.z);
      kf[c*8+6]=bflo(u.w); kf[c*8+7]=bfhi(u.w);
    }
    float dots[20];
    #pragma unroll
    for (int ks = 0; ks < 20; ++ks){
      const float4* qp = (const float4*)(qs + ks * 64);
      float acc = 0.f;
      #pragma unroll
      for (int c = 0; c < 16; ++c){
        float4 q4 = qp[c];
        acc += q4.x * kf[c*4+0] + q4.y * kf[c*4+1] + q4.z * kf[c*4+2] + q4.w * kf[c*4+3];
      }
      dots[ks] = acc * 0.125f;   // DS^-0.5
    }
    float mx = dots[0];
    #pragma unroll
    for (int ks = 1; ks < 20; ++ks) mx = fmaxf(mx, dots[ks]);
    float p[20]; float sum = 0.f;
    #pragma unroll
    for (int ks = 0; ks < 20; ++ks){ p[ks] = __expf(dots[ks] - mx); sum += p[ks]; }
    float inv = 1.f / sum;
    #pragma unroll
    for (int ks = 0; ks < 20; ++ks){
      float a = p[ks] * inv;
      p[ks] = a;
      attnT[ks][t] = a;
      if (write_attn) attn_out[((size_t)b * 20 + ks) * 4096 + n] = a;
    }
    #pragma unroll
    for (int ks = 0; ks < 20; ++ks){
      float vsum = p[ks];
      #pragma unroll
      for (int off = 32; off >= 1; off >>= 1) vsum += __shfl_xor(vsum, off);
      if ((t & 63) == 0) atomicAdd(&Sws[b * 20 + ks], vsum);
    }
  }
  __syncthreads();

  // phase 2: thread (d, nc): u[k] = sum over its 64 n of attn*v
  {
    int d = t & 63, nc = t >> 6;
    const unsigned short* vp = kv + ((size_t)(b * 4096 + n0 + nc * 64)) * 128 + 64 + d;
    float vf[64];
    #pragma unroll
    for (int nn = 0; nn < 64; ++nn) vf[nn] = bflo((unsigned int)vp[(size_t)nn * 128]);
    #pragma unroll
    for (int ks = 0; ks < 20; ++ks){
      const float4* ap = (const float4*)(&attnT[ks][nc * 64]);
      float a = 0.f;
      #pragma unroll
      for (int c = 0; c < 16; ++c){
        float4 a4 = ap[c];
        a += a4.x * vf[c*4+0] + a4.y * vf[c*4+1] + a4.z * vf[c*4+2] + a4.w * vf[c*4+3];
      }
      ured[nc][d][ks] = a;
    }
  }
  __syncthreads();

  #pragma unroll
  for (int j = 0; j < 5; ++j){
    int o = t + 256 * j;             // 1280 outputs
    int dd = o & 63, k3 = o >> 6;
    float s = ured[0][dd][k3] + ured[1][dd][k3] + ured[2][dd][k3] + ured[3][dd][k3];
    atomicAdd(&Uws[((size_t)b * 20 + k3) * 64 + dd], s);
  }
}

// ---------------------------------------------------------------------------
// updates=U/(S+eps) -> GRU -> LN -> MLP -> slots ; one wave per (b,k)
__global__ __launch_bounds__(64) void k_gru(
    float* __restrict__ slots, const float* __restrict__ Uws, const float* __restrict__ Sws,
    const float* __restrict__ Wih, const float* __restrict__ Whh,
    const float* __restrict__ bih, const float* __restrict__ bhh,
    const float* __restrict__ lmg, const float* __restrict__ lmb,
    const float* __restrict__ W1, const float* __restrict__ b1,
    const float* __restrict__ W2, const float* __restrict__ b2,
    float* __restrict__ out_slots, int last){
  int bk = blockIdx.x, d = threadIdx.x;
  float rs = 1.f / (Sws[bk] + 1e-8f);
  float u = Uws[bk * 64 + d] * rs;
  float prev = slots[bk * 64 + d];
  __shared__ __align__(16) float ush[64], psh[64], hsh[64], hidsh[256];
  ush[d] = u; psh[d] = prev;
  __syncthreads();
  float g_i[3], g_h[3];
  #pragma unroll
  for (int g = 0; g < 3; ++g){
    const float4* wi = (const float4*)(Wih + (size_t)(g * 64 + d) * 64);
    const float4* wh = (const float4*)(Whh + (size_t)(g * 64 + d) * 64);
    const float4* u4 = (const float4*)ush;
    const float4* p4 = (const float4*)psh;
    float ai = bih[g * 64 + d], ah = bhh[g * 64 + d];
    #pragma unroll
    for (int c = 0; c < 16; ++c){
      float4 wiv = wi[c], whv = wh[c], uv = u4[c], pv = p4[c];
      ai += wiv.x*uv.x + wiv.y*uv.y + wiv.z*uv.z + wiv.w*uv.w;
      ah += whv.x*pv.x + whv.y*pv.y + whv.z*pv.z + whv.w*pv.w;
    }
    g_i[g] = ai; g_h[g] = ah;
  }
  float r = 1.f / (1.f + __expf(-(g_i[0] + g_h[0])));
  float z = 1.f / (1.f + __expf(-(g_i[1] + g_h[1])));
  float nv = tanhf(g_i[2] + r * g_h[2]);
  float snew = (1.f - z) * nv + z * prev;
  // LayerNorm(snew)
  float s1 = snew, s2 = snew * snew;
  #pragma unroll
  for (int off = 32; off >= 1; off >>= 1){
    s1 += __shfl_xor(s1, off);
    s2 += __shfl_xor(s2, off);
  }
  float m = s1 * (1.f / 64.f);
  float var = s2 * (1.f / 64.f) - m * m;
  float rstd = rsqrtf(var + 1e-5f);
  float h = (snew - m) * rstd * lmg[d] + lmb[d];
  hsh[d] = h;
  __syncthreads();
  float hid[4];
  #pragma unroll
  for (int jj = 0; jj < 4; ++jj){
    int j = jj * 64 + d;
    float a = b1[j];
    #pragma unroll
    for (int i = 0; i < 64; ++i) a += hsh[i] * W1[i * 256 + j];
    hid[jj] = fmaxf(a, 0.f);
  }
  #pragma unroll
  for (int jj = 0; jj < 4; ++jj) hidsh[jj * 64 + d] = hid[jj];
  __syncthreads();
  float o = b2[d];
  #pragma unroll 8
  for (int j = 0; j < 256; ++j) o += hidsh[j] * W2[j * 64 + d];
  float sf = snew + o;
  slots[bk * 64 + d] = sf;
  if (last) out_slots[bk * 64 + d] = sf;
}

// ---------------------------------------------------------------------------
extern "C" void kernel_launch(void* const* d_in, const int* in_sizes, int n_in,
                              void* d_out, int out_size, void* d_ws, size_t ws_size,
                              hipStream_t stream){
  const float* inputs = (const float*)d_in[0];
  const float* noise  = (const float*)d_in[1];
  const float* mu     = (const float*)d_in[2];
  const float* lsig   = (const float*)d_in[3];
  const float* ln_in_g= (const float*)d_in[4];
  const float* ln_in_b= (const float*)d_in[5];
  const float* Wk     = (const float*)d_in[6];
  const float* Wv     = (const float*)d_in[7];
  const float* Wq     = (const float*)d_in[8];
  const float* ln_s_g = (const float*)d_in[9];
  const float* ln_s_b = (const float*)d_in[10];
  const float* Wih    = (const float*)d_in[11];
  const float* Whh    = (const float*)d_in[12];
  const float* bih    = (const float*)d_in[13];
  const float* bhh    = (const float*)d_in[14];
  const float* lmg    = (const float*)d_in[15];
  const float* lmb    = (const float*)d_in[16];
  const float* W1     = (const float*)d_in[17];
  const float* b1     = (const float*)d_in[18];
  const float* W2     = (const float*)d_in[19];
  const float* b2     = (const float*)d_in[20];

  char* ws = (char*)d_ws;
  unsigned short* kv  = (unsigned short*)ws;                 // 67,108,864 B
  unsigned short* Wt  = (unsigned short*)(ws + 67108864);    // 65,536 B
  float* slots        = (float*)(ws + 67174400);             // 327,680 B
  float* qws          = (float*)(ws + 67502080);             // 327,680 B
  float* Uws          = (float*)(ws + 67829760);             // 327,680 B
  float* Sws          = (float*)(ws + 68157440);             // 5,120 B

  float* slots_out = (float*)d_out;
  float* attn_out  = slots_out + 81920;

  hipLaunchKernelGGL(k_wt,   dim3(128),  dim3(256), 0, stream, Wk, Wv, Wt);
  hipLaunchKernelGGL(k_init, dim3(320),  dim3(256), 0, stream, noise, mu, lsig, slots);
  hipLaunchKernelGGL(k_lnkv, dim3(4096), dim3(256), 65536, stream, inputs, ln_in_g, ln_in_b, Wt, kv);

  for (int it = 0; it < 3; ++it){
    hipMemsetAsync(Uws, 0, (81920 + 1280) * sizeof(float), stream);
    hipLaunchKernelGGL(k_slotq, dim3(1280), dim3(64), 0, stream, slots, ln_s_g, ln_s_b, Wq, qws);
    hipLaunchKernelGGL(k_attn, dim3(16, 64), dim3(256), 0, stream, kv, qws, Sws, Uws,
                       attn_out, (it == 2) ? 1 : 0);
    hipLaunchKernelGGL(k_gru, dim3(1280), dim3(64), 0, stream, slots, Uws, Sws,
                       Wih, Whh, bih, bhh, lmg, lmb, W1, b1, W2, b2,
                       slots_out, (it == 2) ? 1 : 0);
  }
}